// Round 3
// baseline (1649.415 us; speedup 1.0000x reference)
//
#include <hip/hip_runtime.h>
#include <hip/hip_bf16.h>
#include <cstdint>
#include <cstddef>

// Problem constants (match reference setup_inputs)
static constexpr int NFEAT   = 512;
static constexpr int NHID    = 128;
static constexpr int NLAYERS = 6;
static constexpr int NCLASS  = 64;

typedef __bf16 bf16x8 __attribute__((ext_vector_type(8)));
typedef float  floatx4 __attribute__((ext_vector_type(4)));

static __device__ __forceinline__ uint16_t f2bf(float v){
    __hip_bfloat16 h = __float2bfloat16(v);
    return *reinterpret_cast<uint16_t*>(&h);
}

// ---------------- dtype sniffer ----------------
// If the float inputs are fp32 (not bf16), the low uint16 words of x are random
// mantissa bits -> ~1/256 match the bf16 inf/NaN exponent pattern. bf16 N(0,1)
// data has zero such words. flags[0]=1 => inputs are fp32.
__global__ void k_sniff(const uint16_t* __restrict__ x, int nwords, uint32_t* __restrict__ flag){
    int i = blockIdx.x*256 + threadIdx.x;
    if (i < nwords){
        uint16_t w = x[i];
        if ((w & 0x7F80u) == 0x7F80u) atomicOr(flag, 1u);
    }
}

// ---------------- diagnostic sentinel (ws too small) ----------------
__global__ void k_sentinel(uint16_t* out, int nel){
    int i = blockIdx.x*256 + threadIdx.x;
    if (i < nel) out[i] = 0x3E00u;   // bf16 0.125
}

// ---------------- CSR build ----------------

__global__ void k_zero(uint32_t* p, int n){
    int i = blockIdx.x*256 + threadIdx.x;
    if (i < n) p[i] = 0u;
}

__global__ void k_hist(const int* __restrict__ rows, uint32_t* __restrict__ deg, int nE){
    int e = blockIdx.x*256 + threadIdx.x;
    if (e < nE) atomicAdd(&deg[rows[e]], 1u);
}

__global__ __launch_bounds__(1024) void k_scan1(const uint32_t* __restrict__ deg,
                                                uint32_t* __restrict__ row_start,
                                                uint32_t* __restrict__ partial, int n){
    __shared__ uint32_t sh[1024];
    int tid = threadIdx.x;
    int i = blockIdx.x*1024 + tid;
    uint32_t v = (i < n) ? deg[i] : 0u;
    sh[tid] = v; __syncthreads();
    for (int off = 1; off < 1024; off <<= 1){
        uint32_t t = (tid >= off) ? sh[tid-off] : 0u;
        __syncthreads();
        sh[tid] += t;
        __syncthreads();
    }
    if (i < n) row_start[i+1] = sh[tid];        // chunk-local inclusive
    if (tid == 1023) partial[blockIdx.x] = sh[1023];
}

__global__ __launch_bounds__(128) void k_scan2(uint32_t* partial, int nb){
    __shared__ uint32_t sh[128];
    int tid = threadIdx.x;
    uint32_t v = (tid < nb) ? partial[tid] : 0u;
    sh[tid] = v; __syncthreads();
    for (int off = 1; off < 128; off <<= 1){
        uint32_t t = (tid >= off) ? sh[tid-off] : 0u;
        __syncthreads();
        sh[tid] += t;
        __syncthreads();
    }
    if (tid < nb) partial[tid] = sh[tid] - v;   // exclusive
}

__global__ __launch_bounds__(1024) void k_scan3(const uint32_t* __restrict__ deg,
                                                uint32_t* __restrict__ row_start,
                                                const uint32_t* __restrict__ partial,
                                                uint32_t* __restrict__ cursor, int n){
    int i = blockIdx.x*1024 + threadIdx.x;
    if (i < n){
        uint32_t rs = row_start[i+1] + partial[blockIdx.x];
        row_start[i+1] = rs;
        cursor[i] = rs - deg[i];                // exclusive start for scatter
        if (i == 0) row_start[0] = 0u;
    }
}

__global__ void k_scatter(const int* __restrict__ rows, const int* __restrict__ cols,
                          const void* __restrict__ vals,
                          uint32_t* __restrict__ cursor, uint2* __restrict__ ep, int nE,
                          const uint32_t* __restrict__ flags){
    int e = blockIdx.x*256 + threadIdx.x;
    if (e < nE){
        int r = rows[e];
        uint32_t pos = atomicAdd(&cursor[r], 1u);
        float v;
        if (flags[0]) v = ((const float*)vals)[e];
        else          v = __bfloat162float(((const __hip_bfloat16*)vals)[e]);
        ep[pos] = make_uint2((uint32_t)cols[e], __float_as_uint(v));
    }
}

// ------------- weight transpose+canonicalize: Bt[n][k] = bf16(B[elem_off + k*N + n]) -------------
// elem_off lets the host address Wh[layer] without knowing the dtype (byte size differs).
__global__ void k_transpose(const void* __restrict__ B, long elem_off,
                            uint16_t* __restrict__ Bt, int K, int N,
                            const uint32_t* __restrict__ flags){
    int idx = blockIdx.x*256 + threadIdx.x;
    if (idx < K*N){
        int k = idx / N, nn = idx - k*N;
        uint16_t w;
        if (flags[0]) w = f2bf(((const float*)B)[elem_off + idx]);
        else          w = ((const uint16_t*)B)[elem_off + idx];
        Bt[nn*K + k] = w;
    }
}

// ---------------- MFMA GEMM: C[M,N] = A[M,K] @ B[K,N], N = NTILES*16 ----------------
// A row-major (lda elems): bf16 canonical, or fp32 when (flagsp && flagsp[0]).
// Bt row-major [N][ldb] bf16 canonical. One wave -> 16 rows x N cols; 4 waves/block.
// MODE 0: write bf16 C (ldc = NTILES*16).  MODE 1: f32 C += result.
template<int NTILES, int MODE>
__global__ __launch_bounds__(256) void k_gemm(
    const void* __restrict__ Aany, int lda,
    const uint16_t* __restrict__ Bt, int ldb, int K, int Mwaves,
    uint16_t* __restrict__ Cb, float* __restrict__ Cf,
    const uint32_t* __restrict__ flagsp)
{
    __shared__ uint16_t lds[NTILES*16*40];   // padded rows of 40 elems (80 B, 16B-aligned)
    const int tid  = threadIdx.x;
    const int lane = tid & 63;
    const int gw   = blockIdx.x*4 + (tid >> 6);
    const bool active = gw < Mwaves;
    const int m = lane & 15, quad = lane >> 4;
    const long row0 = (long)gw * 16;
    const int afp32 = flagsp ? (int)flagsp[0] : 0;
    const uint16_t* A16 = (const uint16_t*)Aany;
    const float*    A32 = (const float*)Aany;

    floatx4 acc[NTILES];
#pragma unroll
    for (int i = 0; i < NTILES; i++) acc[i] = (floatx4){0.f,0.f,0.f,0.f};

    for (int kk = 0; kk < K; kk += 32){
        for (int idx = tid; idx < NTILES*16*4; idx += 256){
            int nn = idx >> 2, c = idx & 3;
            *(bf16x8*)&lds[nn*40 + c*8] = *(const bf16x8*)&Bt[(long)nn*ldb + kk + c*8];
        }
        __syncthreads();
        if (active){
            bf16x8 a;
            if (afp32){
                const float* p = &A32[(row0 + m)*lda + kk + quad*8];
                float4 f0 = *(const float4*)p;
                float4 f1 = *(const float4*)(p + 4);
                a[0]=(__bf16)f0.x; a[1]=(__bf16)f0.y; a[2]=(__bf16)f0.z; a[3]=(__bf16)f0.w;
                a[4]=(__bf16)f1.x; a[5]=(__bf16)f1.y; a[6]=(__bf16)f1.z; a[7]=(__bf16)f1.w;
            } else {
                a = *(const bf16x8*)&A16[(row0 + m)*lda + kk + quad*8];
            }
#pragma unroll
            for (int nt = 0; nt < NTILES; nt++){
                bf16x8 b = *(const bf16x8*)&lds[(nt*16 + m)*40 + quad*8];
                acc[nt] = __builtin_amdgcn_mfma_f32_16x16x32_bf16(a, b, acc[nt], 0, 0, 0);
            }
        }
        __syncthreads();
    }
    if (active){
#pragma unroll
        for (int nt = 0; nt < NTILES; nt++){
#pragma unroll
            for (int r = 0; r < 4; r++){
                long row = row0 + quad*4 + r;       // C/D: row = (lane>>4)*4 + reg
                int  col = nt*16 + m;               //      col = lane&15
                float v = acc[nt][r];
                if (MODE == 1) Cf[row*(NTILES*16) + col] += v;
                else           Cb[row*(NTILES*16) + col] = f2bf(v);
            }
        }
    }
}

// ------- SpMM: out[row,:] = relu( sum_e val_e * tmp[col_e,:] ), 1 wave/row, bf16 [n][128] -------
__global__ __launch_bounds__(256) void k_spmm(
    const uint2* __restrict__ ep, const uint32_t* __restrict__ row_start,
    const uint32_t* __restrict__ tmp, uint16_t* __restrict__ out, int n)
{
    int t = blockIdx.x*256 + threadIdx.x;
    int gw = t >> 6, lane = t & 63;
    if (gw >= n) return;
    uint32_t s = row_start[gw], e = row_start[gw+1];
    float ax = 0.f, ay = 0.f;
    for (uint32_t j = s; j < e; j++){
        uint2 d = ep[j];
        float v = __uint_as_float(d.y);
        uint32_t p = tmp[(size_t)d.x*64 + lane];        // features (2*lane, 2*lane+1)
        ax = fmaf(v, __uint_as_float(p << 16), ax);
        ay = fmaf(v, __uint_as_float(p & 0xffff0000u), ay);
    }
    ax = fmaxf(ax, 0.f); ay = fmaxf(ay, 0.f);
    uint32_t packed = ((uint32_t)f2bf(ay) << 16) | (uint32_t)f2bf(ax);
    *(uint32_t*)&out[(size_t)gw*128 + 2*lane] = packed;
}

// ---------------- log_softmax over 64 classes (+bias), 1 wave/row ----------------
__global__ __launch_bounds__(256) void k_logsoftmax(const float* __restrict__ logits,
                                                    const void* __restrict__ bias,
                                                    void* __restrict__ out, int n,
                                                    const uint32_t* __restrict__ flags){
    int t = blockIdx.x*256 + threadIdx.x;
    int row = t >> 6, lane = t & 63;
    if (row >= n) return;
    const int fp32 = (int)flags[0];
    float b = fp32 ? ((const float*)bias)[lane]
                   : __bfloat162float(((const __hip_bfloat16*)bias)[lane]);
    float x = logits[(size_t)row*64 + lane] + b;
    float mx = x;
    for (int off = 32; off; off >>= 1) mx = fmaxf(mx, __shfl_xor(mx, off));
    float ex = __expf(x - mx);
    float sum = ex;
    for (int off = 32; off; off >>= 1) sum += __shfl_xor(sum, off);
    float r = x - mx - __logf(sum);
    if (fp32) ((float*)out)[(size_t)row*64 + lane] = r;
    else      ((uint16_t*)out)[(size_t)row*64 + lane] = f2bf(r);
}

// ---------------- launch ----------------
extern "C" void kernel_launch(void* const* d_in, const int* in_sizes, int n_in,
                              void* d_out, int out_size, void* d_ws, size_t ws_size,
                              hipStream_t stream){
    const void* x    = d_in[0];                 // [n,512] bf16 or fp32 (sniffed on device)
    const int* rows  = (const int*)d_in[1];
    const int* cols  = (const int*)d_in[2];
    const void* vals = d_in[3];
    const void* Wh   = d_in[5];                 // [5,128,128]
    const void* Wfc  = d_in[6];                 // [768,64]
    const void* bfc  = d_in[7];
    const void* W0   = d_in[4];                 // [512,128]

    const int n  = in_sizes[0] / NFEAT;    // 100000
    const int nE = in_sizes[1];            // 1.6M

    char* ws = (char*)d_ws;
    size_t off = 0;
    auto alloc = [&](size_t bytes)->char*{
        char* p = ws + off;
        off = (off + bytes + 255) & ~(size_t)255;
        return p;
    };
    uint32_t* flags     = (uint32_t*)alloc(256);
    uint32_t* deg       = (uint32_t*)alloc((size_t)n*4);
    uint32_t* row_start = (uint32_t*)alloc(((size_t)n+1)*4);
    uint32_t* cursor    = (uint32_t*)alloc((size_t)n*4);
    uint32_t* partial   = (uint32_t*)alloc(512);
    uint2*    ep        = (uint2*)   alloc((size_t)nE*8);
    uint16_t* W0t       = (uint16_t*)alloc((size_t)NFEAT*NHID*2);
    uint16_t* Wht       = (uint16_t*)alloc((size_t)(NLAYERS-1)*NHID*NHID*2);
    uint16_t* Wfct      = (uint16_t*)alloc((size_t)NCLASS*NLAYERS*NHID*2);  // [64][768]
    uint16_t* tmp       = (uint16_t*)alloc((size_t)n*NHID*2);     // bf16 [n,128]
    uint16_t* hbuf      = (uint16_t*)alloc((size_t)n*NHID*2);     // bf16 [n,128]
    float*    logits    = (float*)   alloc((size_t)n*NCLASS*4);   // f32 [n,64]
    // total ws need: ~91 MB

    if (ws_size < off){
        k_sentinel<<<(out_size+255)/256, 256, 0, stream>>>((uint16_t*)d_out, out_size);
        return;
    }

    hipMemsetAsync(flags, 0, 4, stream);
    const int NW = 1 << 20;   // sniff first 1M uint16 words of x (in-bounds either dtype)
    k_sniff<<<NW/256, 256, 0, stream>>>((const uint16_t*)x, NW, flags);

    const int scanBlocks = (n + 1023)/1024;
    k_zero<<<(n+255)/256, 256, 0, stream>>>(deg, n);
    k_hist<<<(nE+255)/256, 256, 0, stream>>>(rows, deg, nE);
    k_scan1<<<scanBlocks, 1024, 0, stream>>>(deg, row_start, partial, n);
    k_scan2<<<1, 128, 0, stream>>>(partial, scanBlocks);
    k_scan3<<<scanBlocks, 1024, 0, stream>>>(deg, row_start, partial, cursor, n);
    k_scatter<<<(nE+255)/256, 256, 0, stream>>>(rows, cols, vals, cursor, ep, nE, flags);

    k_transpose<<<(NFEAT*NHID+255)/256, 256, 0, stream>>>(W0, 0L, W0t, NFEAT, NHID, flags);
    for (int l = 0; l < NLAYERS-1; l++)
        k_transpose<<<(NHID*NHID+255)/256, 256, 0, stream>>>(
            Wh, (long)l*NHID*NHID, Wht + l*NHID*NHID, NHID, NHID, flags);
    k_transpose<<<(NLAYERS*NHID*NCLASS+255)/256, 256, 0, stream>>>(
            Wfc, 0L, Wfct, NLAYERS*NHID, NCLASS, flags);

    hipMemsetAsync(logits, 0, (size_t)n*NCLASS*4, stream);

    const int Mwaves = n/16;                 // 100000 % 16 == 0
    const int gemmBlocks = (Mwaves + 3)/4;
    const int rowBlocks  = (n*64 + 255)/256; // 1 wave/row kernels

    // layer 0: tmp = x @ W0 ; h = relu(spmm(tmp)) ; logits += h @ Wfc[0:128,:]
    k_gemm<8,0><<<gemmBlocks, 256, 0, stream>>>(x, NFEAT, W0t, NFEAT, NFEAT, Mwaves, tmp, nullptr, flags);
    k_spmm<<<rowBlocks, 256, 0, stream>>>(ep, row_start, (const uint32_t*)tmp, hbuf, n);
    k_gemm<4,1><<<gemmBlocks, 256, 0, stream>>>(hbuf, NHID, Wfct, NLAYERS*NHID, NHID,
                                                Mwaves, nullptr, logits, nullptr);
    // layers 1..5
    for (int l = 1; l < NLAYERS; l++){
        k_gemm<8,0><<<gemmBlocks, 256, 0, stream>>>(hbuf, NHID, Wht + (l-1)*NHID*NHID, NHID, NHID,
                                                    Mwaves, tmp, nullptr, nullptr);
        k_spmm<<<rowBlocks, 256, 0, stream>>>(ep, row_start, (const uint32_t*)tmp, hbuf, n);
        k_gemm<4,1><<<gemmBlocks, 256, 0, stream>>>(hbuf, NHID, Wfct + l*NHID, NLAYERS*NHID, NHID,
                                                    Mwaves, nullptr, logits, nullptr);
    }
    // out = log_softmax(logits + bfc)
    k_logsoftmax<<<rowBlocks, 256, 0, stream>>>(logits, bfc, d_out, n, flags);
}

// Round 4
// 1231.588 us; speedup vs baseline: 1.3393x; 1.3393x over previous
//
#include <hip/hip_runtime.h>
#include <hip/hip_bf16.h>
#include <cstdint>
#include <cstddef>

static constexpr int NFEAT   = 512;
static constexpr int NHID    = 128;
static constexpr int NLAYERS = 6;
static constexpr int NCLASS  = 64;

typedef __bf16 bf16x8 __attribute__((ext_vector_type(8)));
typedef float  floatx4 __attribute__((ext_vector_type(4)));

static __device__ __forceinline__ uint16_t f2bf(float v){
    __hip_bfloat16 h = __float2bfloat16(v);
    return *reinterpret_cast<uint16_t*>(&h);
}

// ---------------- dtype sniffer (bf16 vs fp32 inputs) ----------------
__global__ void k_sniff(const uint16_t* __restrict__ x, int nwords, uint32_t* __restrict__ flag){
    int i = blockIdx.x*256 + threadIdx.x;
    if (i < nwords){
        uint16_t w = x[i];
        if ((w & 0x7F80u) == 0x7F80u) atomicOr(flag, 1u);
    }
}

// ---------------- diagnostic sentinel (ws too small) ----------------
__global__ void k_sentinel(uint16_t* out, int nel){
    int i = blockIdx.x*256 + threadIdx.x;
    if (i < nel) out[i] = 0x3E00u;   // bf16 0.125
}

// ---------------- CSR build ----------------
__global__ void k_zero(uint32_t* p, int n){
    int i = blockIdx.x*256 + threadIdx.x;
    if (i < n) p[i] = 0u;
}

__global__ void k_hist(const int* __restrict__ rows, uint32_t* __restrict__ deg, int nE){
    int e = blockIdx.x*256 + threadIdx.x;
    if (e < nE) atomicAdd(&deg[rows[e]], 1u);
}

__global__ __launch_bounds__(1024) void k_scan1(const uint32_t* __restrict__ deg,
                                                uint32_t* __restrict__ row_start,
                                                uint32_t* __restrict__ partial, int n){
    __shared__ uint32_t sh[1024];
    int tid = threadIdx.x;
    int i = blockIdx.x*1024 + tid;
    uint32_t v = (i < n) ? deg[i] : 0u;
    sh[tid] = v; __syncthreads();
    for (int off = 1; off < 1024; off <<= 1){
        uint32_t t = (tid >= off) ? sh[tid-off] : 0u;
        __syncthreads();
        sh[tid] += t;
        __syncthreads();
    }
    if (i < n) row_start[i+1] = sh[tid];
    if (tid == 1023) partial[blockIdx.x] = sh[1023];
}

__global__ __launch_bounds__(128) void k_scan2(uint32_t* partial, int nb){
    __shared__ uint32_t sh[128];
    int tid = threadIdx.x;
    uint32_t v = (tid < nb) ? partial[tid] : 0u;
    sh[tid] = v; __syncthreads();
    for (int off = 1; off < 128; off <<= 1){
        uint32_t t = (tid >= off) ? sh[tid-off] : 0u;
        __syncthreads();
        sh[tid] += t;
        __syncthreads();
    }
    if (tid < nb) partial[tid] = sh[tid] - v;
}

__global__ __launch_bounds__(1024) void k_scan3(const uint32_t* __restrict__ deg,
                                                uint32_t* __restrict__ row_start,
                                                const uint32_t* __restrict__ partial,
                                                uint32_t* __restrict__ cursor, int n){
    int i = blockIdx.x*1024 + threadIdx.x;
    if (i < n){
        uint32_t rs = row_start[i+1] + partial[blockIdx.x];
        row_start[i+1] = rs;
        cursor[i] = rs - deg[i];
        if (i == 0) row_start[0] = 0u;
    }
}

__global__ void k_scatter(const int* __restrict__ rows, const int* __restrict__ cols,
                          const void* __restrict__ vals,
                          uint32_t* __restrict__ cursor, uint2* __restrict__ ep, int nE,
                          const uint32_t* __restrict__ flags){
    int e = blockIdx.x*256 + threadIdx.x;
    if (e < nE){
        int r = rows[e];
        uint32_t pos = atomicAdd(&cursor[r], 1u);
        float v;
        if (flags[0]) v = ((const float*)vals)[e];
        else          v = __bfloat162float(((const __hip_bfloat16*)vals)[e]);
        ep[pos] = make_uint2((uint32_t)cols[e], __float_as_uint(v));
    }
}

// ---- weight transpose+canonicalize: Bt[n][k] = bf16(B[elem_off + k*N + n]) ----
__global__ void k_transpose(const void* __restrict__ B, long elem_off,
                            uint16_t* __restrict__ Bt, int K, int N,
                            const uint32_t* __restrict__ flags){
    int idx = blockIdx.x*256 + threadIdx.x;
    if (idx < K*N){
        int k = idx / N, nn = idx - k*N;
        uint16_t w;
        if (flags[0]) w = f2bf(((const float*)B)[elem_off + idx]);
        else          w = ((const uint16_t*)B)[elem_off + idx];
        Bt[nn*K + k] = w;
    }
}

// ---------------- generic MFMA GEMM (kept for layer-0 and final accum) ----------------
// MODE 0: write bf16 C (ldc = NTILES*16).  MODE 1: f32 C += result.
template<int NTILES, int MODE>
__global__ __launch_bounds__(256) void k_gemm(
    const void* __restrict__ Aany, int lda,
    const uint16_t* __restrict__ Bt, int ldb, int K, int Mwaves,
    uint16_t* __restrict__ Cb, float* __restrict__ Cf,
    const uint32_t* __restrict__ flagsp)
{
    __shared__ uint16_t lds[NTILES*16*40];
    const int tid  = threadIdx.x;
    const int lane = tid & 63;
    const int gw   = blockIdx.x*4 + (tid >> 6);
    const bool active = gw < Mwaves;
    const int m = lane & 15, quad = lane >> 4;
    const long row0 = (long)gw * 16;
    const int afp32 = flagsp ? (int)flagsp[0] : 0;
    const uint16_t* A16 = (const uint16_t*)Aany;
    const float*    A32 = (const float*)Aany;

    floatx4 acc[NTILES];
#pragma unroll
    for (int i = 0; i < NTILES; i++) acc[i] = (floatx4){0.f,0.f,0.f,0.f};

    for (int kk = 0; kk < K; kk += 32){
        for (int idx = tid; idx < NTILES*16*4; idx += 256){
            int nn = idx >> 2, c = idx & 3;
            *(bf16x8*)&lds[nn*40 + c*8] = *(const bf16x8*)&Bt[(long)nn*ldb + kk + c*8];
        }
        __syncthreads();
        if (active){
            bf16x8 a;
            if (afp32){
                const float* p = &A32[(row0 + m)*lda + kk + quad*8];
                float4 f0 = *(const float4*)p;
                float4 f1 = *(const float4*)(p + 4);
                a[0]=(__bf16)f0.x; a[1]=(__bf16)f0.y; a[2]=(__bf16)f0.z; a[3]=(__bf16)f0.w;
                a[4]=(__bf16)f1.x; a[5]=(__bf16)f1.y; a[6]=(__bf16)f1.z; a[7]=(__bf16)f1.w;
            } else {
                a = *(const bf16x8*)&A16[(row0 + m)*lda + kk + quad*8];
            }
#pragma unroll
            for (int nt = 0; nt < NTILES; nt++){
                bf16x8 b = *(const bf16x8*)&lds[(nt*16 + m)*40 + quad*8];
                acc[nt] = __builtin_amdgcn_mfma_f32_16x16x32_bf16(a, b, acc[nt], 0, 0, 0);
            }
        }
        __syncthreads();
    }
    if (active){
#pragma unroll
        for (int nt = 0; nt < NTILES; nt++){
#pragma unroll
            for (int r = 0; r < 4; r++){
                long row = row0 + quad*4 + r;       // C/D: row = (lane>>4)*4 + reg
                int  col = nt*16 + m;               //      col = lane&15
                float v = acc[nt][r];
                if (MODE == 1) Cf[row*(NTILES*16) + col] += v;
                else           Cb[row*(NTILES*16) + col] = f2bf(v);
            }
        }
    }
}

// ---------------- fused layer GEMM: C1 = A@B1 (bf16), C2 += A@B2 (f32) ----------------
// A: hbuf [n][128] bf16. B1t: [128][128] bf16 (Wh^T). B2t: rows of Wfct [64][ldb2],
// k-slice starts at the given pointer. Whole B resident in LDS; one barrier;
// grid-stride waves over 16-row chunks.
__global__ __launch_bounds__(256) void k_gemm_fused(
    const uint16_t* __restrict__ A,
    const uint16_t* __restrict__ B1t,
    const uint16_t* __restrict__ B2t, int ldb2,
    uint16_t* __restrict__ C1, float* __restrict__ C2, int nchunks)
{
    __shared__ uint16_t lds[(128+64)*132];   // B1 rows then B2 rows, 132-elem pitch
    const int tid = threadIdx.x, lane = tid & 63;
    for (int idx = tid; idx < 128*16; idx += 256){
        int nn = idx >> 4, c = idx & 15;
        *(bf16x8*)&lds[nn*132 + c*8] = *(const bf16x8*)&B1t[nn*128 + c*8];
    }
    for (int idx = tid; idx < 64*16; idx += 256){
        int nn = idx >> 4, c = idx & 15;
        *(bf16x8*)&lds[(128+nn)*132 + c*8] = *(const bf16x8*)&B2t[(long)nn*ldb2 + c*8];
    }
    __syncthreads();

    const int m = lane & 15, quad = lane >> 4;
    const int nw = gridDim.x * 4;
    for (int chunk = blockIdx.x*4 + (tid >> 6); chunk < nchunks; chunk += nw){
        const long row0 = (long)chunk * 16;
        const uint16_t* Arow = &A[(row0 + m)*128 + quad*8];
        bf16x8 a[4];
#pragma unroll
        for (int ks = 0; ks < 4; ks++) a[ks] = *(const bf16x8*)&Arow[ks*32];

        floatx4 acc1[8], acc2[4];
#pragma unroll
        for (int i = 0; i < 8; i++) acc1[i] = (floatx4){0.f,0.f,0.f,0.f};
#pragma unroll
        for (int i = 0; i < 4; i++) acc2[i] = (floatx4){0.f,0.f,0.f,0.f};

#pragma unroll
        for (int ks = 0; ks < 4; ks++){
            const int kk = ks*32 + quad*8;
#pragma unroll
            for (int nt = 0; nt < 8; nt++){
                bf16x8 b = *(const bf16x8*)&lds[(nt*16 + m)*132 + kk];
                acc1[nt] = __builtin_amdgcn_mfma_f32_16x16x32_bf16(a[ks], b, acc1[nt], 0, 0, 0);
            }
#pragma unroll
            for (int nt = 0; nt < 4; nt++){
                bf16x8 b = *(const bf16x8*)&lds[(128 + nt*16 + m)*132 + kk];
                acc2[nt] = __builtin_amdgcn_mfma_f32_16x16x32_bf16(a[ks], b, acc2[nt], 0, 0, 0);
            }
        }
        // C1: bf16, paired-lane dword stores (lane m even writes cols {col, col+1})
#pragma unroll
        for (int nt = 0; nt < 8; nt++){
#pragma unroll
            for (int r = 0; r < 4; r++){
                long row = row0 + quad*4 + r;
                int  col = nt*16 + m;
                float v  = acc1[nt][r];
                float vn = __shfl_xor(v, 1);
                if ((m & 1) == 0){
                    uint32_t pk = (uint32_t)f2bf(v) | ((uint32_t)f2bf(vn) << 16);
                    *(uint32_t*)&C1[row*128 + col] = pk;
                }
            }
        }
        // C2: f32 accumulate, paired-lane float2 RMW
#pragma unroll
        for (int nt = 0; nt < 4; nt++){
#pragma unroll
            for (int r = 0; r < 4; r++){
                long row = row0 + quad*4 + r;
                int  col = nt*16 + m;
                float v  = acc2[nt][r];
                float vn = __shfl_xor(v, 1);
                if ((m & 1) == 0){
                    float2* p = (float2*)&C2[row*64 + col];
                    float2 o = *p;
                    o.x += v; o.y += vn;
                    *p = o;
                }
            }
        }
    }
}

// ------- SpMM v2: out[row,:] = relu( sum_e val_e * tmp[col_e,:] ), 1 wave/row -------
// Edge metadata batch-loaded coalesced (lane j -> edge j), broadcast via shfl,
// gathers unrolled x4 for MLP (memory-level parallelism).
__global__ __launch_bounds__(256) void k_spmm(
    const uint2* __restrict__ ep, const uint32_t* __restrict__ row_start,
    const uint32_t* __restrict__ tmp, uint16_t* __restrict__ out, int n)
{
    int t = blockIdx.x*256 + threadIdx.x;
    int gw = t >> 6, lane = t & 63;
    if (gw >= n) return;
    uint32_t s = row_start[gw], e = row_start[gw+1];
    float ax = 0.f, ay = 0.f;
    for (uint32_t base = s; base < e; base += 64){
        int cnt = (int)(e - base); if (cnt > 64) cnt = 64;
        uint2 d = (lane < cnt) ? ep[base + lane] : make_uint2(0u, 0u);
        int j = 0;
        for (; j + 4 <= cnt; j += 4){
            uint32_t c0 = __shfl(d.x, j+0); float v0 = __uint_as_float(__shfl(d.y, j+0));
            uint32_t c1 = __shfl(d.x, j+1); float v1 = __uint_as_float(__shfl(d.y, j+1));
            uint32_t c2 = __shfl(d.x, j+2); float v2 = __uint_as_float(__shfl(d.y, j+2));
            uint32_t c3 = __shfl(d.x, j+3); float v3 = __uint_as_float(__shfl(d.y, j+3));
            uint32_t p0 = tmp[(size_t)c0*64 + lane];
            uint32_t p1 = tmp[(size_t)c1*64 + lane];
            uint32_t p2 = tmp[(size_t)c2*64 + lane];
            uint32_t p3 = tmp[(size_t)c3*64 + lane];
            ax = fmaf(v0, __uint_as_float(p0 << 16), ax); ay = fmaf(v0, __uint_as_float(p0 & 0xffff0000u), ay);
            ax = fmaf(v1, __uint_as_float(p1 << 16), ax); ay = fmaf(v1, __uint_as_float(p1 & 0xffff0000u), ay);
            ax = fmaf(v2, __uint_as_float(p2 << 16), ax); ay = fmaf(v2, __uint_as_float(p2 & 0xffff0000u), ay);
            ax = fmaf(v3, __uint_as_float(p3 << 16), ax); ay = fmaf(v3, __uint_as_float(p3 & 0xffff0000u), ay);
        }
        for (; j < cnt; j++){
            uint32_t c = __shfl(d.x, j); float v = __uint_as_float(__shfl(d.y, j));
            uint32_t p = tmp[(size_t)c*64 + lane];
            ax = fmaf(v, __uint_as_float(p << 16), ax);
            ay = fmaf(v, __uint_as_float(p & 0xffff0000u), ay);
        }
    }
    ax = fmaxf(ax, 0.f); ay = fmaxf(ay, 0.f);
    uint32_t packed = ((uint32_t)f2bf(ay) << 16) | (uint32_t)f2bf(ax);
    *(uint32_t*)&out[(size_t)gw*128 + 2*lane] = packed;
}

// ---------------- log_softmax over 64 classes (+bias), 1 wave/row ----------------
__global__ __launch_bounds__(256) void k_logsoftmax(const float* __restrict__ logits,
                                                    const void* __restrict__ bias,
                                                    void* __restrict__ out, int n,
                                                    const uint32_t* __restrict__ flags){
    int t = blockIdx.x*256 + threadIdx.x;
    int row = t >> 6, lane = t & 63;
    if (row >= n) return;
    const int fp32 = (int)flags[0];
    float b = fp32 ? ((const float*)bias)[lane]
                   : __bfloat162float(((const __hip_bfloat16*)bias)[lane]);
    float x = logits[(size_t)row*64 + lane] + b;
    float mx = x;
    for (int off = 32; off; off >>= 1) mx = fmaxf(mx, __shfl_xor(mx, off));
    float ex = __expf(x - mx);
    float sum = ex;
    for (int off = 32; off; off >>= 1) sum += __shfl_xor(sum, off);
    float r = x - mx - __logf(sum);
    if (fp32) ((float*)out)[(size_t)row*64 + lane] = r;
    else      ((uint16_t*)out)[(size_t)row*64 + lane] = f2bf(r);
}

// ---------------- launch ----------------
extern "C" void kernel_launch(void* const* d_in, const int* in_sizes, int n_in,
                              void* d_out, int out_size, void* d_ws, size_t ws_size,
                              hipStream_t stream){
    const void* x    = d_in[0];
    const int* rows  = (const int*)d_in[1];
    const int* cols  = (const int*)d_in[2];
    const void* vals = d_in[3];
    const void* W0   = d_in[4];
    const void* Wh   = d_in[5];
    const void* Wfc  = d_in[6];
    const void* bfc  = d_in[7];

    const int n  = in_sizes[0] / NFEAT;    // 100000
    const int nE = in_sizes[1];            // 1.6M

    char* ws = (char*)d_ws;
    size_t off = 0;
    auto alloc = [&](size_t bytes)->char*{
        char* p = ws + off;
        off = (off + bytes + 255) & ~(size_t)255;
        return p;
    };
    uint32_t* flags     = (uint32_t*)alloc(256);
    uint32_t* deg       = (uint32_t*)alloc((size_t)n*4);
    uint32_t* row_start = (uint32_t*)alloc(((size_t)n+1)*4);
    uint32_t* cursor    = (uint32_t*)alloc((size_t)n*4);
    uint32_t* partial   = (uint32_t*)alloc(512);
    uint2*    ep        = (uint2*)   alloc((size_t)nE*8);
    uint16_t* W0t       = (uint16_t*)alloc((size_t)NFEAT*NHID*2);
    uint16_t* Wht       = (uint16_t*)alloc((size_t)(NLAYERS-1)*NHID*NHID*2);
    uint16_t* Wfct      = (uint16_t*)alloc((size_t)NCLASS*NLAYERS*NHID*2);  // [64][768]
    uint16_t* tmp       = (uint16_t*)alloc((size_t)n*NHID*2);
    uint16_t* hbuf      = (uint16_t*)alloc((size_t)n*NHID*2);
    float*    logits    = (float*)   alloc((size_t)n*NCLASS*4);

    if (ws_size < off){
        k_sentinel<<<(out_size+255)/256, 256, 0, stream>>>((uint16_t*)d_out, out_size);
        return;
    }

    hipMemsetAsync(flags, 0, 4, stream);
    const int NW = 1 << 20;
    k_sniff<<<NW/256, 256, 0, stream>>>((const uint16_t*)x, NW, flags);

    const int scanBlocks = (n + 1023)/1024;
    k_zero<<<(n+255)/256, 256, 0, stream>>>(deg, n);
    k_hist<<<(nE+255)/256, 256, 0, stream>>>(rows, deg, nE);
    k_scan1<<<scanBlocks, 1024, 0, stream>>>(deg, row_start, partial, n);
    k_scan2<<<1, 128, 0, stream>>>(partial, scanBlocks);
    k_scan3<<<scanBlocks, 1024, 0, stream>>>(deg, row_start, partial, cursor, n);
    k_scatter<<<(nE+255)/256, 256, 0, stream>>>(rows, cols, vals, cursor, ep, nE, flags);

    k_transpose<<<(NFEAT*NHID+255)/256, 256, 0, stream>>>(W0, 0L, W0t, NFEAT, NHID, flags);
    for (int l = 0; l < NLAYERS-1; l++)
        k_transpose<<<(NHID*NHID+255)/256, 256, 0, stream>>>(
            Wh, (long)l*NHID*NHID, Wht + l*NHID*NHID, NHID, NHID, flags);
    k_transpose<<<(NLAYERS*NHID*NCLASS+255)/256, 256, 0, stream>>>(
            Wfc, 0L, Wfct, NLAYERS*NHID, NCLASS, flags);

    hipMemsetAsync(logits, 0, (size_t)n*NCLASS*4, stream);

    const int Mwaves = n/16;                 // 6250
    const int gemmBlocks = (Mwaves + 3)/4;   // 1563
    const int rowBlocks  = (n*64 + 255)/256;
    const int fusedBlocks = 768;             // 3 blocks/CU (LDS-limited occupancy)

    // layer 0: tmp = x @ W0 ; h0 = relu(spmm(tmp))
    k_gemm<8,0><<<gemmBlocks, 256, 0, stream>>>(x, NFEAT, W0t, NFEAT, NFEAT, Mwaves, tmp, nullptr, flags);
    k_spmm<<<rowBlocks, 256, 0, stream>>>(ep, row_start, (const uint32_t*)tmp, hbuf, n);
    // layers 1..5: fused (tmp = h_{l-1}@Wh_{l-1}, logits += h_{l-1}@Wfc_{l-1}), then spmm
    for (int l = 1; l < NLAYERS; l++){
        k_gemm_fused<<<fusedBlocks, 256, 0, stream>>>(hbuf, Wht + (l-1)*NHID*NHID,
                                                      Wfct + (l-1)*NHID, NLAYERS*NHID,
                                                      tmp, logits, Mwaves);
        k_spmm<<<rowBlocks, 256, 0, stream>>>(ep, row_start, (const uint32_t*)tmp, hbuf, n);
    }
    // final: logits += h5 @ Wfc_5 ; out = log_softmax(logits + bfc)
    k_gemm<4,1><<<gemmBlocks, 256, 0, stream>>>(hbuf, NHID, Wfct + (NLAYERS-1)*NHID, NLAYERS*NHID,
                                                NHID, Mwaves, nullptr, logits, nullptr);
    k_logsoftmax<<<rowBlocks, 256, 0, stream>>>(logits, bfc, d_out, n, flags);
}